// Round 10
// baseline (679.588 us; speedup 1.0000x reference)
//
#include <hip/hip_runtime.h>
#include <hip/hip_bf16.h>
#include <stdint.h>

#define M_DIM 8192
#define K_DIM 14336
#define N_DIM 4096
#define GROUP_SZ 128
#define NGROUP (K_DIM / GROUP_SZ)   // 112

typedef short short8 __attribute__((ext_vector_type(8)));
typedef float f32x4 __attribute__((ext_vector_type(4)));
typedef int i32x4 __attribute__((ext_vector_type(4)));

// fp32 -> bf16 raw bits, round-to-nearest-even (fallback tiers)
static __device__ __forceinline__ short f2bf(float f) {
  unsigned u = __builtin_bit_cast(unsigned, f);
  u += 0x7FFFu + ((u >> 16) & 1u);
  return (short)(u >> 16);
}

// async global->LDS, 16B per lane (dest = wave-uniform base + lane*16)
static __device__ __forceinline__ void gload_lds16(const void* g, void* lds) {
  __builtin_amdgcn_global_load_lds(
      (const __attribute__((address_space(1))) unsigned int*)g,
      (__attribute__((address_space(3))) unsigned int*)lds, 16, 0, 0);
}

// ---------------- pre-pass kernels (i8 tier) ----------------

// per-row absmax quantize: qx f32 [M,K] -> i8 [M,K], sx[m] = absmax/127
__global__ __launch_bounds__(256) void dp_quant_x(const float* __restrict__ x,
                                                  char* __restrict__ xq,
                                                  float* __restrict__ sx) {
  __shared__ float rowbuf[K_DIM];
  __shared__ float red[256];
  const int row = blockIdx.x;
  const int t = threadIdx.x;
  const float* xr = x + (size_t)row * K_DIM;
  float amax = 0.f;
#pragma unroll
  for (int j = 0; j < 14; ++j) {
    float4 v = *(const float4*)(xr + j * 1024 + t * 4);
    *(float4*)(rowbuf + j * 1024 + t * 4) = v;
    amax = fmaxf(amax,
                 fmaxf(fmaxf(fabsf(v.x), fabsf(v.y)), fmaxf(fabsf(v.z), fabsf(v.w))));
  }
  red[t] = amax;
  __syncthreads();
  for (int s = 128; s > 0; s >>= 1) {
    if (t < s) red[t] = fmaxf(red[t], red[t + s]);
    __syncthreads();
  }
  const float am = red[0];
  const float inv = (am > 0.f) ? 127.f / am : 0.f;
  if (t == 0) sx[row] = am * (1.f / 127.f);
  char* xo = xq + (size_t)row * K_DIM;
#pragma unroll
  for (int j = 0; j < 14; ++j) {
    float4 v = *(const float4*)(rowbuf + j * 1024 + t * 4);
    char4 q;
    q.x = (char)__float2int_rn(v.x * inv);
    q.y = (char)__float2int_rn(v.y * inv);
    q.z = (char)__float2int_rn(v.z * inv);
    q.w = (char)__float2int_rn(v.w * inv);
    *(char4*)(xo + j * 1024 + t * 4) = q;
  }
}

// int4 + per-group scales -> per-row-requantized i8 [N,K], sw[n] = 8*max_g(ws)/127.
__global__ __launch_bounds__(256) void dp_repack_w(const int* __restrict__ wq,
                                                   const float* __restrict__ wsc,
                                                   char* __restrict__ w8,
                                                   float* __restrict__ sw) {
  __shared__ float wsl[NGROUP];
  const int n = blockIdx.x;
  const int t = threadIdx.x;
  if (t < NGROUP) wsl[t] = wsc[(size_t)n * NGROUP + t];
  __syncthreads();
  float mx = 0.f;
#pragma unroll
  for (int g = 0; g < NGROUP; ++g) mx = fmaxf(mx, wsl[g]);
  const float invsw = 15.875f / mx;  // 127/(8*mx)
  if (t == 0) sw[n] = mx * (8.f / 127.f);
#pragma unroll
  for (int j = 0; j < 7; ++j) {
    int p = t + 256 * j;  // 0..1791, coalesced
    int w = wq[(size_t)n * (K_DIM / 8) + p];
    float sc = wsl[p >> 4] * invsw;
    unsigned lo = 0, hi = 0;
#pragma unroll
    for (int b = 0; b < 4; ++b) {
      int q = (w << (28 - 4 * b)) >> 28;
      int r = __float2int_rn((float)q * sc);
      lo |= (unsigned)(r & 0xff) << (8 * b);
    }
#pragma unroll
    for (int b = 4; b < 8; ++b) {
      int q = (w << (28 - 4 * b)) >> 28;
      int r = __float2int_rn((float)q * sc);
      hi |= (unsigned)(r & 0xff) << (8 * (b - 4));
    }
    *(uint2*)(w8 + (size_t)n * K_DIM + (size_t)p * 8) = make_uint2(lo, hi);
  }
}

// ---------------- Tier-1 GEMM: i8, 256x128 tile, BK=64, triple-buffered -----
// Occupancy-targeted variant: wave tile 64x64 (acc=64 i32), 8 waves (4wm x 2wn),
// __launch_bounds__(512,4) caps unified regs at 128/wave -> 4 waves/SIMD
// (2 blocks/CU; LDS 72KB = 3 slots x (A 16KB + B 8KB), 2x72 <= 160KB).
// Rows are 64B = 4 slots of 16B; phys_slot = log_slot ^ ((row>>1)&3)
// (R7-verified: zero bank conflicts). Linear gload_lds dest + inverse-swizzled
// global source + swizzled ds_read (both-sides rule).
// Interval T: {8 ds_read (tile T) | stage tile T+2 (3 gloads) | vmcnt(3) |
// barrier | 16 mfma_i32_16x16x64_i8 chained-C}. Triple-buffer: stage at T
// targets slot of tile T-1, last read one interval (1 barrier + DMA latency)
// earlier. vmcnt(3) at T drains tile T+1 (staged at T-1) before T+1's reads.
__global__ __launch_bounds__(512, 4) void dp_gemm8i(
    const char* __restrict__ Xq, const char* __restrict__ Wq8,
    const float* __restrict__ sw, const float* __restrict__ sx,
    const float* __restrict__ qxscale, const float* __restrict__ residual,
    const float* __restrict__ bias, float* __restrict__ out) {
  __shared__ __align__(16) char lds[73728];

  const int tid = threadIdx.x;
  const int lane = tid & 63;
  const int wid = tid >> 6;
  const int wm = wid >> 1, wn = wid & 1;  // 4 x 2 waves, 64x64 each
  const int lr = lane & 15, lg = lane >> 4;

  // XCD-bijective swizzle (nwg = 1024, 1024 % 8 == 0)
  const int wg = blockIdx.x;
  const int swz = (wg & 7) * 128 + (wg >> 3);
  const int m0 = (swz >> 5) * 256;  // 32 m-tiles
  const int n0 = (swz & 31) * 128;  // 32 n-tiles

  // fragment ds byte-offsets (64B rows, 4 slots of 16B)
  const int slot16 = (lg ^ ((lr >> 1) & 3)) << 4;
  int offA[4], offB[4];
#pragma unroll
  for (int mf = 0; mf < 4; ++mf)
    offA[mf] = (wm * 64 + mf * 16 + lr) * 64 + slot16;  // rows 0..255
#pragma unroll
  for (int nf = 0; nf < 4; ++nf)
    offB[nf] = (wn * 64 + nf * 16 + lr) * 64 + slot16;  // rows 0..127

  // staging: rows of 64B, 4 threads/row; inverse-swizzled global k offset
  const int srow = tid >> 2;                              // 0..127
  const int ksrc = ((tid & 3) ^ ((srow >> 1) & 3)) * 16;  // pre-swizzled k byte
  const char* gA = Xq + (size_t)(m0 + srow) * K_DIM + ksrc;  // +128*K for h1
  const char* gB = Wq8 + (size_t)(n0 + srow) * K_DIM + ksrc;
  const int dst0 = tid * 16;

  // triple-buffer slot pointers (rotated; no runtime-indexed arrays, rule #20)
  char *a0 = lds, *a1 = lds + 16384, *a2 = lds + 32768;
  char *b0 = lds + 49152, *b1 = lds + 57344, *b2 = lds + 65536;

  i32x4 acc[4][4];  // [mf][nf], chained through MFMA C (AGPR)
#pragma unroll
  for (int i = 0; i < 4; ++i)
#pragma unroll
    for (int j = 0; j < 4; ++j) acc[i][j] = (i32x4){0, 0, 0, 0};

#define STAGE(kb, pa, pb)                                                      \
  do {                                                                         \
    gload_lds16(gA + (size_t)(kb), (pa) + dst0);                               \
    gload_lds16(gA + (size_t)(kb) + (size_t)128 * K_DIM, (pa) + 8192 + dst0);  \
    gload_lds16(gB + (size_t)(kb), (pb) + dst0);                               \
  } while (0)

#define FENCE asm volatile("" ::: "memory")

  // ---- prologue: stage tiles 0,1; drain tile 0 (keep tile 1's 3) ----
  STAGE(0, a0, b0);
  STAGE(64, a1, b1);
  FENCE;
  asm volatile("s_waitcnt vmcnt(3)" ::: "memory");
  __builtin_amdgcn_s_barrier();
  FENCE;

  // ---- main loop: 224 K-tiles ----
  for (int T = 0; T < 224; ++T) {
    i32x4 aF[4], bF[4];
#pragma unroll
    for (int mf = 0; mf < 4; ++mf) aF[mf] = *(const i32x4*)(a0 + offA[mf]);
#pragma unroll
    for (int nf = 0; nf < 4; ++nf) bF[nf] = *(const i32x4*)(b0 + offB[nf]);
    if (T < 222) STAGE((size_t)(T + 2) * 64, a2, b2);
    FENCE;
    if (T < 222) asm volatile("s_waitcnt vmcnt(3)" ::: "memory");
    else         asm volatile("s_waitcnt vmcnt(0)" ::: "memory");
    __builtin_amdgcn_s_barrier();
    FENCE;
    __builtin_amdgcn_s_setprio(1);
#pragma unroll
    for (int mf = 0; mf < 4; ++mf)
#pragma unroll
      for (int nf = 0; nf < 4; ++nf)
        acc[mf][nf] = __builtin_amdgcn_mfma_i32_16x16x64_i8(aF[mf], bF[nf],
                                                            acc[mf][nf], 0, 0, 0);
    __builtin_amdgcn_s_setprio(0);
    FENCE;
    // rotate triple buffers
    char* t0 = a0; a0 = a1; a1 = a2; a2 = t0;
    char* t1 = b0; b0 = b1; b1 = b2; b2 = t1;
  }

  // ---- epilogue: y = acc * (sx[m]*qxscale[m]*sw[n]) + residual + bias[n] ----
#pragma unroll
  for (int mf = 0; mf < 4; ++mf)
#pragma unroll
    for (int nf = 0; nf < 4; ++nf) {
      int n = n0 + wn * 64 + nf * 16 + lr;
      float bv = bias[n];
      float swn = sw[n];
      i32x4 v = acc[mf][nf];
#pragma unroll
      for (int rr = 0; rr < 4; ++rr) {
        int m = m0 + wm * 64 + mf * 16 + lg * 4 + rr;
        size_t off = (size_t)m * N_DIM + n;
        out[off] = (float)v[rr] * (qxscale[m] * sx[m] * swn) + residual[off] + bv;
      }
    }
#undef STAGE
#undef FENCE
}

// ---------------- fallback pre-pass + GEMM (tiers 2/3, bf16) ----------------

__global__ __launch_bounds__(256) void dp_dequant_w(const int* __restrict__ wq,
                                                    const float* __restrict__ wsc,
                                                    short* __restrict__ wb) {
  int p = blockIdx.x * 256 + threadIdx.x;
  int n = blockIdx.y;
  int w = wq[(size_t)n * (K_DIM / 8) + p];
  float sc = wsc[(size_t)n * NGROUP + (p >> 4)];
  short8 v;
#pragma unroll
  for (int j = 0; j < 8; ++j) {
    int q = (w << (28 - 4 * j)) >> 28;
    v[j] = f2bf((float)q * sc);
  }
  *(short8*)(wb + (size_t)n * K_DIM + (size_t)p * 8) = v;
}

template <int BMODE>
__global__ __launch_bounds__(256) void dp_gemm(
    const float* __restrict__ qx, const int* __restrict__ Wq,
    const float* __restrict__ Wsc, const short* __restrict__ Wb,
    const float* __restrict__ qxscale, const float* __restrict__ residual,
    const float* __restrict__ bias, float* __restrict__ out) {
  __shared__ short As[128 * 64];
  __shared__ short Bs[128 * 64];

  const int tid = threadIdx.x;
  const int lane = tid & 63;
  const int w = tid >> 6;

  const int nwg = gridDim.x;
  const int cpx = nwg >> 3;
  const int wg = blockIdx.x;
  const int swz = (wg & 7) * cpx + (wg >> 3);
  const int bm = swz / (N_DIM / 128);
  const int bn = swz % (N_DIM / 128);
  const int m0 = bm * 128, n0 = bn * 128;

  const int wm = w >> 1, wn = w & 1;
  const int lr = lane & 15, lg = lane >> 4;

  f32x4 acc[4][4];
#pragma unroll
  for (int i = 0; i < 4; ++i)
#pragma unroll
    for (int j = 0; j < 4; ++j) acc[i][j] = (f32x4){0.f, 0.f, 0.f, 0.f};

  for (int kt = 0; kt < K_DIM / 64; ++kt) {
    const int k0 = kt * 64;
#pragma unroll
    for (int i = 0; i < 4; ++i) {
      int ldsb = i * 4096 + tid * 16;
      int row = ldsb >> 7;
      int slog = ((ldsb >> 4) & 7) ^ (row & 7);
      const float4* p = (const float4*)(qx + (size_t)(m0 + row) * K_DIM + k0 + slog * 8);
      float4 u0 = p[0], u1 = p[1];
      short8 v;
      v[0] = f2bf(u0.x); v[1] = f2bf(u0.y); v[2] = f2bf(u0.z); v[3] = f2bf(u0.w);
      v[4] = f2bf(u1.x); v[5] = f2bf(u1.y); v[6] = f2bf(u1.z); v[7] = f2bf(u1.w);
      *(short8*)((char*)As + ldsb) = v;
    }
    if (BMODE == 0) {
#pragma unroll
      for (int i = 0; i < 4; ++i) {
        int ldsb = i * 4096 + w * 1024 + lane * 16;
        int row = ldsb >> 7;
        int slog = ((ldsb >> 4) & 7) ^ (row & 7);
        gload_lds16(Wb + (size_t)(n0 + row) * K_DIM + k0 + slog * 8, (char*)Bs + ldsb);
      }
    } else {
      int row = tid >> 1;
      int kb = (tid & 1) * 32;
      int4 pw = *(const int4*)(Wq + (size_t)(n0 + row) * (K_DIM / 8) + (k0 + kb) / 8);
      float sc = Wsc[(size_t)(n0 + row) * NGROUP + (k0 + kb) / GROUP_SZ];
      int pv[4] = {pw.x, pw.y, pw.z, pw.w};
#pragma unroll
      for (int p = 0; p < 4; ++p) {
        short8 v;
#pragma unroll
        for (int j = 0; j < 8; ++j) {
          int q = (pv[p] << (28 - 4 * j)) >> 28;
          v[j] = f2bf((float)q * sc);
        }
        int slog = (tid & 1) * 4 + p;
        int sp = slog ^ (row & 7);
        *(short8*)((char*)Bs + row * 128 + sp * 16) = v;
      }
    }
    __syncthreads();
#pragma unroll
    for (int s = 0; s < 2; ++s) {
      short8 a[4], b[4];
#pragma unroll
      for (int f = 0; f < 4; ++f) {
        int row = wm * 64 + f * 16 + lr;
        int sp = (s * 4 + lg) ^ (row & 7);
        a[f] = *(const short8*)((char*)As + row * 128 + sp * 16);
      }
#pragma unroll
      for (int f = 0; f < 4; ++f) {
        int row = wn * 64 + f * 16 + lr;
        int sp = (s * 4 + lg) ^ (row & 7);
        b[f] = *(const short8*)((char*)Bs + row * 128 + sp * 16);
      }
#pragma unroll
      for (int i = 0; i < 4; ++i)
#pragma unroll
        for (int j = 0; j < 4; ++j)
          acc[i][j] = __builtin_amdgcn_mfma_f32_16x16x32_bf16(a[i], b[j], acc[i][j], 0, 0, 0);
    }
    __syncthreads();
  }

  const int mb = m0 + wm * 64, nb = n0 + wn * 64;
#pragma unroll
  for (int i = 0; i < 4; ++i)
#pragma unroll
    for (int j = 0; j < 4; ++j) {
      int n = nb + j * 16 + lr;
      float bv = bias[n];
#pragma unroll
      for (int r = 0; r < 4; ++r) {
        int m = mb + i * 16 + lg * 4 + r;
        size_t off = (size_t)m * N_DIM + n;
        out[off] = acc[i][j][r] * qxscale[m] + residual[off] + bv;
      }
    }
}

extern "C" void kernel_launch(void* const* d_in, const int* in_sizes, int n_in,
                              void* d_out, int out_size, void* d_ws, size_t ws_size,
                              hipStream_t stream) {
  const float* qx = (const float*)d_in[0];
  const float* qxscale = (const float*)d_in[1];
  const float* residual = (const float*)d_in[2];
  const int* wq = (const int*)d_in[3];
  const float* wsc = (const float*)d_in[4];
  const float* bias = (const float*)d_in[5];
  float* out = (float*)d_out;

  // i8-tier workspace layout
  const size_t SZ_W8 = (size_t)N_DIM * K_DIM;                 // 58,720,256
  const size_t SZ_XQ = (size_t)M_DIM * K_DIM;                 // 117,440,512
  const size_t OFF_XQ = SZ_W8;
  const size_t OFF_SW = OFF_XQ + SZ_XQ;
  const size_t OFF_SX = OFF_SW + (size_t)N_DIM * 4;
  const size_t need_i8 = OFF_SX + (size_t)M_DIM * 4;          // ~176 MB
  const size_t need_w = (size_t)N_DIM * K_DIM * 2;            // bf16 fallback

  if (ws_size >= need_i8) {
    char* w8 = (char*)d_ws;
    char* xq = (char*)d_ws + OFF_XQ;
    float* sw = (float*)((char*)d_ws + OFF_SW);
    float* sx = (float*)((char*)d_ws + OFF_SX);
    dp_repack_w<<<dim3(N_DIM), dim3(256), 0, stream>>>(wq, wsc, w8, sw);
    dp_quant_x<<<dim3(M_DIM), dim3(256), 0, stream>>>(qx, xq, sx);
    dp_gemm8i<<<dim3((M_DIM / 256) * (N_DIM / 128)), dim3(512), 0, stream>>>(
        xq, w8, sw, sx, qxscale, residual, bias, out);
  } else if (ws_size >= need_w) {
    short* wb = (short*)d_ws;
    dp_dequant_w<<<dim3(K_DIM / 8 / 256, N_DIM), dim3(256), 0, stream>>>(wq, wsc, wb);
    dp_gemm<0><<<dim3(2048), dim3(256), 0, stream>>>(qx, wq, wsc, wb, qxscale,
                                                     residual, bias, out);
  } else {
    dp_gemm<1><<<dim3(2048), dim3(256), 0, stream>>>(qx, wq, wsc, nullptr, qxscale,
                                                     residual, bias, out);
  }
}

// Round 11
// 505.911 us; speedup vs baseline: 1.3433x; 1.3433x over previous
//
#include <hip/hip_runtime.h>
#include <hip/hip_bf16.h>
#include <stdint.h>

#define M_DIM 8192
#define K_DIM 14336
#define N_DIM 4096
#define GROUP_SZ 128
#define NGROUP (K_DIM / GROUP_SZ)   // 112

typedef short short8 __attribute__((ext_vector_type(8)));
typedef float f32x4 __attribute__((ext_vector_type(4)));
typedef int i32x4 __attribute__((ext_vector_type(4)));

// fp32 -> bf16 raw bits, round-to-nearest-even (fallback tiers)
static __device__ __forceinline__ short f2bf(float f) {
  unsigned u = __builtin_bit_cast(unsigned, f);
  u += 0x7FFFu + ((u >> 16) & 1u);
  return (short)(u >> 16);
}

// async global->LDS, 16B per lane (dest = wave-uniform base + lane*16)
static __device__ __forceinline__ void gload_lds16(const void* g, void* lds) {
  __builtin_amdgcn_global_load_lds(
      (const __attribute__((address_space(1))) unsigned int*)g,
      (__attribute__((address_space(3))) unsigned int*)lds, 16, 0, 0);
}

// ---------------- pre-pass kernels (i8 tier) ----------------

// per-row absmax quantize: qx f32 [M,K] -> i8 [M,K], sx[m] = absmax/127
__global__ __launch_bounds__(256) void dp_quant_x(const float* __restrict__ x,
                                                  char* __restrict__ xq,
                                                  float* __restrict__ sx) {
  __shared__ float rowbuf[K_DIM];
  __shared__ float red[256];
  const int row = blockIdx.x;
  const int t = threadIdx.x;
  const float* xr = x + (size_t)row * K_DIM;
  float amax = 0.f;
#pragma unroll
  for (int j = 0; j < 14; ++j) {
    float4 v = *(const float4*)(xr + j * 1024 + t * 4);
    *(float4*)(rowbuf + j * 1024 + t * 4) = v;
    amax = fmaxf(amax,
                 fmaxf(fmaxf(fabsf(v.x), fabsf(v.y)), fmaxf(fabsf(v.z), fabsf(v.w))));
  }
  red[t] = amax;
  __syncthreads();
  for (int s = 128; s > 0; s >>= 1) {
    if (t < s) red[t] = fmaxf(red[t], red[t + s]);
    __syncthreads();
  }
  const float am = red[0];
  const float inv = (am > 0.f) ? 127.f / am : 0.f;
  if (t == 0) sx[row] = am * (1.f / 127.f);
  char* xo = xq + (size_t)row * K_DIM;
#pragma unroll
  for (int j = 0; j < 14; ++j) {
    float4 v = *(const float4*)(rowbuf + j * 1024 + t * 4);
    char4 q;
    q.x = (char)__float2int_rn(v.x * inv);
    q.y = (char)__float2int_rn(v.y * inv);
    q.z = (char)__float2int_rn(v.z * inv);
    q.w = (char)__float2int_rn(v.w * inv);
    *(char4*)(xo + j * 1024 + t * 4) = q;
  }
}

// int4 + per-group scales -> per-row-requantized i8 [N,K], sw[n] = 8*max_g(ws)/127.
// w8 = round(iw * ws[g] / sw[n]); |w8| <= 127 by construction (exact i32 GEMM after).
__global__ __launch_bounds__(256) void dp_repack_w(const int* __restrict__ wq,
                                                   const float* __restrict__ wsc,
                                                   char* __restrict__ w8,
                                                   float* __restrict__ sw) {
  __shared__ float wsl[NGROUP];
  const int n = blockIdx.x;
  const int t = threadIdx.x;
  if (t < NGROUP) wsl[t] = wsc[(size_t)n * NGROUP + t];
  __syncthreads();
  float mx = 0.f;
#pragma unroll
  for (int g = 0; g < NGROUP; ++g) mx = fmaxf(mx, wsl[g]);
  const float invsw = 15.875f / mx;  // 127/(8*mx)
  if (t == 0) sw[n] = mx * (8.f / 127.f);
#pragma unroll
  for (int j = 0; j < 7; ++j) {
    int p = t + 256 * j;  // 0..1791, coalesced
    int w = wq[(size_t)n * (K_DIM / 8) + p];
    float sc = wsl[p >> 4] * invsw;
    unsigned lo = 0, hi = 0;
#pragma unroll
    for (int b = 0; b < 4; ++b) {
      int q = (w << (28 - 4 * b)) >> 28;
      int r = __float2int_rn((float)q * sc);
      lo |= (unsigned)(r & 0xff) << (8 * b);
    }
#pragma unroll
    for (int b = 4; b < 8; ++b) {
      int q = (w << (28 - 4 * b)) >> 28;
      int r = __float2int_rn((float)q * sc);
      hi |= (unsigned)(r & 0xff) << (8 * (b - 4));
    }
    *(uint2*)(w8 + (size_t)n * K_DIM + (size_t)p * 8) = make_uint2(lo, hi);
  }
}

// ---------------- Tier-1 GEMM: i8, 256x256 tile, BK=128, 8-phase ------------
// R4's proven phase geometry with i8 payload (best-verified: R8 bench 385us).
// LDS 128KB: A doubled-tile (parity) at (T&1)<<15 (256 rows x 128B = 32KB);
// B at +65536. Row = 8 slots of 16B, phys_slot = log_slot ^ (row&7); linear
// gload_lds dest + inverse-swizzled global source + swizzled ds_read.
// Per phase: one quadrant (mh,nh), 12 ds_read_b128, 16 mfma_i32_16x16x64_i8
// (4mf x 2nf x 2kk) with i32 acc CHAINED through C (exact; < 2^31).
// Stage stmt = 2 gload_lds16 (16KB half-tile); single barrier/phase,
// vmcnt(4) at phases 4/8 (keeps 2 newest stage stmts).
__global__ __launch_bounds__(512, 2) void dp_gemm8i(
    const char* __restrict__ Xq, const char* __restrict__ Wq8,
    const float* __restrict__ sw, const float* __restrict__ sx,
    const float* __restrict__ qxscale, const float* __restrict__ residual,
    const float* __restrict__ bias, float* __restrict__ out) {
  __shared__ __align__(16) char lds[131072];

  const int tid = threadIdx.x;
  const int lane = tid & 63;
  const int wid = tid >> 6;
  const int wm = wid >> 2, wn = wid & 3;   // 2 x 4 waves
  const int lr = lane & 15, lg = lane >> 4;

  // XCD-bijective swizzle (nwg = 512, 512 % 8 == 0)
  const int wg = blockIdx.x;
  const int swz = (wg & 7) * 64 + (wg >> 3);
  const int m0 = (swz >> 4) * 256;
  const int n0 = (swz & 15) * 256;

  // fragment ds byte-offsets within a 32KB tile buffer (mh/nh added as <<14)
  int offA[4][2], offB[2][2];
#pragma unroll
  for (int mf = 0; mf < 4; ++mf) {
    int r = wm * 64 + mf * 16 + lr;  // 0..127 (mh adds 128 = +16KB, r&7 invariant)
#pragma unroll
    for (int kk = 0; kk < 2; ++kk)
      offA[mf][kk] = r * 128 + (((kk * 4 + lg) ^ (r & 7)) << 4);
  }
#pragma unroll
  for (int nf = 0; nf < 2; ++nf) {
    int r = wn * 32 + nf * 16 + lr;
#pragma unroll
    for (int kk = 0; kk < 2; ++kk)
      offB[nf][kk] = r * 128 + (((kk * 4 + lg) ^ (r & 7)) << 4);
  }

  // staging: 2 gload_lds16 per thread per 16KB half-tile, linear LDS dest,
  // inverse-swizzled global k offset (rows are 128B = 8 slots)
  const int srow = tid >> 3;                              // 0..63
  const int ksrc = ((tid & 7) ^ (srow & 7)) * 16;         // inverse-swizzled k byte
  const size_t aRow = (size_t)(m0 + srow) * K_DIM + ksrc;
  const size_t bRow = (size_t)(n0 + srow) * K_DIM + ksrc;
  const int dst0 = tid * 16;

  i32x4 acc[8][4];  // [mh*4+mf][nh*2+nf], chained through MFMA C (AGPR)
#pragma unroll
  for (int i = 0; i < 8; ++i)
#pragma unroll
    for (int j = 0; j < 4; ++j) acc[i][j] = (i32x4){0, 0, 0, 0};

  i32x4 aF[4][2];     // A frags for current (T, mh) [mf][kk]
  i32x4 bF[2][2][2];  // B frags [nh][nf][kk], resident per doubled K-tile

#define STAGE_A(T, h)                                                          \
  do {                                                                         \
    size_t g_ = aRow + (size_t)((h) * 128) * K_DIM + (size_t)(T) * 128;        \
    int d_ = (((T) & 1) << 15) + ((h) << 14) + dst0;                           \
    gload_lds16(Xq + g_, lds + d_);                                            \
    gload_lds16(Xq + g_ + (size_t)64 * K_DIM, lds + d_ + 8192);                \
  } while (0)

#define STAGE_B(T, h)                                                          \
  do {                                                                         \
    size_t g_ = bRow + (size_t)((h) * 128) * K_DIM + (size_t)(T) * 128;        \
    int d_ = 65536 + (((T) & 1) << 15) + ((h) << 14) + dst0;                   \
    gload_lds16(Wq8 + g_, lds + d_);                                           \
    gload_lds16(Wq8 + g_ + (size_t)64 * K_DIM, lds + d_ + 8192);               \
  } while (0)

#define FENCE asm volatile("" ::: "memory")

  // PHASE: optional A/B fragment loads, stage stmt, counted-wait stmt,
  // ONE barrier, MFMA cluster under setprio.
#define PHASE(T, mh, nh, LA, LB, STMT, WMT)                                    \
  do {                                                                         \
    if (LA) {                                                                  \
      const char* Ab_ = lds + ((((T) & 1) << 15) + ((mh) << 14));              \
      _Pragma("unroll") for (int mf = 0; mf < 4; ++mf)                         \
          _Pragma("unroll") for (int kk = 0; kk < 2; ++kk)                     \
              aF[mf][kk] = *(const i32x4*)(Ab_ + offA[mf][kk]);                \
    }                                                                          \
    if (LB) {                                                                  \
      const char* Bb_ = lds + (65536 + (((T) & 1) << 15) + ((nh) << 14));      \
      _Pragma("unroll") for (int nf = 0; nf < 2; ++nf)                         \
          _Pragma("unroll") for (int kk = 0; kk < 2; ++kk)                     \
              bF[nh][nf][kk] = *(const i32x4*)(Bb_ + offB[nf][kk]);            \
    }                                                                          \
    STMT;                                                                      \
    FENCE;                                                                     \
    WMT;                                                                       \
    __builtin_amdgcn_s_barrier();                                              \
    FENCE;                                                                     \
    __builtin_amdgcn_s_setprio(1);                                             \
    _Pragma("unroll") for (int kk = 0; kk < 2; ++kk)                           \
        _Pragma("unroll") for (int mf = 0; mf < 4; ++mf)                       \
            _Pragma("unroll") for (int nf = 0; nf < 2; ++nf)                   \
                acc[(mh) * 4 + mf][(nh) * 2 + nf] =                            \
                    __builtin_amdgcn_mfma_i32_16x16x64_i8(                     \
                        aF[mf][kk], bF[nh][nf][kk],                            \
                        acc[(mh) * 4 + mf][(nh) * 2 + nf], 0, 0, 0);           \
    __builtin_amdgcn_s_setprio(0);                                             \
    FENCE;                                                                     \
  } while (0)

  // ---- prologue: tile 0 full + tile 1 h0 halves; drain tile 0 ----
  STAGE_A(0, 0); STAGE_B(0, 0); STAGE_A(0, 1); STAGE_B(0, 1);
  STAGE_A(1, 0); STAGE_B(1, 0);
  FENCE;
  asm volatile("s_waitcnt vmcnt(4)" ::: "memory");
  __builtin_amdgcn_s_barrier();
  FENCE;

  // ---- main loop: 56 iterations x 2 doubled K-tiles (K/128 = 112) ----
  for (int i = 0; i < 56; ++i) {
    const int t = 2 * i;
    const bool st = (i < 55);
    PHASE(t, 0, 0, 1, 1, { STAGE_A(t + 1, 1); }, {});
    PHASE(t, 0, 1, 0, 1, { STAGE_B(t + 1, 1); }, {});
    PHASE(t, 1, 0, 1, 0, { if (st) STAGE_A(t + 2, 0); }, {});
    PHASE(t, 1, 1, 0, 0, { if (st) STAGE_B(t + 2, 0); },
          {
            if (st) asm volatile("s_waitcnt vmcnt(4)" ::: "memory");
            else    asm volatile("s_waitcnt vmcnt(0)" ::: "memory");
          });
    PHASE(t + 1, 0, 0, 1, 1, { if (st) STAGE_A(t + 2, 1); }, {});
    PHASE(t + 1, 0, 1, 0, 1, { if (st) STAGE_B(t + 2, 1); }, {});
    PHASE(t + 1, 1, 0, 1, 0, { if (st) STAGE_A(t + 3, 0); }, {});
    PHASE(t + 1, 1, 1, 0, 0, { if (st) STAGE_B(t + 3, 0); },
          {
            if (st) asm volatile("s_waitcnt vmcnt(4)" ::: "memory");
            else    asm volatile("s_waitcnt vmcnt(0)" ::: "memory");
          });
  }

  // ---- epilogue: y = acc * (sx[m]*qxscale[m]*sw[n]) + residual + bias[n] ----
#pragma unroll
  for (int mh = 0; mh < 2; ++mh)
#pragma unroll
    for (int mf = 0; mf < 4; ++mf)
#pragma unroll
      for (int nh = 0; nh < 2; ++nh)
#pragma unroll
        for (int nf = 0; nf < 2; ++nf) {
          int n = n0 + nh * 128 + wn * 32 + nf * 16 + lr;
          float bv = bias[n];
          float swn = sw[n];
          i32x4 v = acc[mh * 4 + mf][nh * 2 + nf];
#pragma unroll
          for (int rr = 0; rr < 4; ++rr) {
            int m = m0 + mh * 128 + wm * 64 + mf * 16 + lg * 4 + rr;
            size_t off = (size_t)m * N_DIM + n;
            out[off] = (float)v[rr] * (qxscale[m] * sx[m] * swn) + residual[off] + bv;
          }
        }
#undef PHASE
#undef STAGE_A
#undef STAGE_B
#undef FENCE
}

// ---------------- fallback pre-pass + GEMM (tiers 2/3, bf16) ----------------

__global__ __launch_bounds__(256) void dp_dequant_w(const int* __restrict__ wq,
                                                    const float* __restrict__ wsc,
                                                    short* __restrict__ wb) {
  int p = blockIdx.x * 256 + threadIdx.x;
  int n = blockIdx.y;
  int w = wq[(size_t)n * (K_DIM / 8) + p];
  float sc = wsc[(size_t)n * NGROUP + (p >> 4)];
  short8 v;
#pragma unroll
  for (int j = 0; j < 8; ++j) {
    int q = (w << (28 - 4 * j)) >> 28;
    v[j] = f2bf((float)q * sc);
  }
  *(short8*)(wb + (size_t)n * K_DIM + (size_t)p * 8) = v;
}

template <int BMODE>
__global__ __launch_bounds__(256) void dp_gemm(
    const float* __restrict__ qx, const int* __restrict__ Wq,
    const float* __restrict__ Wsc, const short* __restrict__ Wb,
    const float* __restrict__ qxscale, const float* __restrict__ residual,
    const float* __restrict__ bias, float* __restrict__ out) {
  __shared__ short As[128 * 64];
  __shared__ short Bs[128 * 64];

  const int tid = threadIdx.x;
  const int lane = tid & 63;
  const int w = tid >> 6;

  const int nwg = gridDim.x;
  const int cpx = nwg >> 3;
  const int wg = blockIdx.x;
  const int swz = (wg & 7) * cpx + (wg >> 3);
  const int bm = swz / (N_DIM / 128);
  const int bn = swz % (N_DIM / 128);
  const int m0 = bm * 128, n0 = bn * 128;

  const int wm = w >> 1, wn = w & 1;
  const int lr = lane & 15, lg = lane >> 4;

  f32x4 acc[4][4];
#pragma unroll
  for (int i = 0; i < 4; ++i)
#pragma unroll
    for (int j = 0; j < 4; ++j) acc[i][j] = (f32x4){0.f, 0.f, 0.f, 0.f};

  for (int kt = 0; kt < K_DIM / 64; ++kt) {
    const int k0 = kt * 64;
#pragma unroll
    for (int i = 0; i < 4; ++i) {
      int ldsb = i * 4096 + tid * 16;
      int row = ldsb >> 7;
      int slog = ((ldsb >> 4) & 7) ^ (row & 7);
      const float4* p = (const float4*)(qx + (size_t)(m0 + row) * K_DIM + k0 + slog * 8);
      float4 u0 = p[0], u1 = p[1];
      short8 v;
      v[0] = f2bf(u0.x); v[1] = f2bf(u0.y); v[2] = f2bf(u0.z); v[3] = f2bf(u0.w);
      v[4] = f2bf(u1.x); v[5] = f2bf(u1.y); v[6] = f2bf(u1.z); v[7] = f2bf(u1.w);
      *(short8*)((char*)As + ldsb) = v;
    }
    if (BMODE == 0) {
#pragma unroll
      for (int i = 0; i < 4; ++i) {
        int ldsb = i * 4096 + w * 1024 + lane * 16;
        int row = ldsb >> 7;
        int slog = ((ldsb >> 4) & 7) ^ (row & 7);
        gload_lds16(Wb + (size_t)(n0 + row) * K_DIM + k0 + slog * 8, (char*)Bs + ldsb);
      }
    } else {
      int row = tid >> 1;
      int kb = (tid & 1) * 32;
      int4 pw = *(const int4*)(Wq + (size_t)(n0 + row) * (K_DIM / 8) + (k0 + kb) / 8);
      float sc = Wsc[(size_t)(n0 + row) * NGROUP + (k0 + kb) / GROUP_SZ];
      int pv[4] = {pw.x, pw.y, pw.z, pw.w};
#pragma unroll
      for (int p = 0; p < 4; ++p) {
        short8 v;
#pragma unroll
        for (int j = 0; j < 8; ++j) {
          int q = (pv[p] << (28 - 4 * j)) >> 28;
          v[j] = f2bf((float)q * sc);
        }
        int slog = (tid & 1) * 4 + p;
        int sp = slog ^ (row & 7);
        *(short8*)((char*)Bs + row * 128 + sp * 16) = v;
      }
    }
    __syncthreads();
#pragma unroll
    for (int s = 0; s < 2; ++s) {
      short8 a[4], b[4];
#pragma unroll
      for (int f = 0; f < 4; ++f) {
        int row = wm * 64 + f * 16 + lr;
        int sp = (s * 4 + lg) ^ (row & 7);
        a[f] = *(const short8*)((char*)As + row * 128 + sp * 16);
      }
#pragma unroll
      for (int f = 0; f < 4; ++f) {
        int row = wn * 64 + f * 16 + lr;
        int sp = (s * 4 + lg) ^ (row & 7);
        b[f] = *(const short8*)((char*)Bs + row * 128 + sp * 16);
      }
#pragma unroll
      for (int i = 0; i < 4; ++i)
#pragma unroll
        for (int j = 0; j < 4; ++j)
          acc[i][j] = __builtin_amdgcn_mfma_f32_16x16x32_bf16(a[i], b[j], acc[i][j], 0, 0, 0);
    }
    __syncthreads();
  }

  const int mb = m0 + wm * 64, nb = n0 + wn * 64;
#pragma unroll
  for (int i = 0; i < 4; ++i)
#pragma unroll
    for (int j = 0; j < 4; ++j) {
      int n = nb + j * 16 + lr;
      float bv = bias[n];
#pragma unroll
      for (int r = 0; r < 4; ++r) {
        int m = mb + i * 16 + lg * 4 + r;
        size_t off = (size_t)m * N_DIM + n;
        out[off] = acc[i][j][r] * qxscale[m] + residual[off] + bv;
      }
    }
}

extern "C" void kernel_launch(void* const* d_in, const int* in_sizes, int n_in,
                              void* d_out, int out_size, void* d_ws, size_t ws_size,
                              hipStream_t stream) {
  const float* qx = (const float*)d_in[0];
  const float* qxscale = (const float*)d_in[1];
  const float* residual = (const float*)d_in[2];
  const int* wq = (const int*)d_in[3];
  const float* wsc = (const float*)d_in[4];
  const float* bias = (const float*)d_in[5];
  float* out = (float*)d_out;

  // i8-tier workspace layout
  const size_t SZ_W8 = (size_t)N_DIM * K_DIM;                 // 58,720,256
  const size_t SZ_XQ = (size_t)M_DIM * K_DIM;                 // 117,440,512
  const size_t OFF_XQ = SZ_W8;
  const size_t OFF_SW = OFF_XQ + SZ_XQ;
  const size_t OFF_SX = OFF_SW + (size_t)N_DIM * 4;
  const size_t need_i8 = OFF_SX + (size_t)M_DIM * 4;          // ~176 MB
  const size_t need_w = (size_t)N_DIM * K_DIM * 2;            // bf16 fallback

  if (ws_size >= need_i8) {
    char* w8 = (char*)d_ws;
    char* xq = (char*)d_ws + OFF_XQ;
    float* sw = (float*)((char*)d_ws + OFF_SW);
    float* sx = (float*)((char*)d_ws + OFF_SX);
    dp_repack_w<<<dim3(N_DIM), dim3(256), 0, stream>>>(wq, wsc, w8, sw);
    dp_quant_x<<<dim3(M_DIM), dim3(256), 0, stream>>>(qx, xq, sx);
    dp_gemm8i<<<dim3((M_DIM / 256) * (N_DIM / 256)), dim3(512), 0, stream>>>(
        xq, w8, sw, sx, qxscale, residual, bias, out);
  } else if (ws_size >= need_w) {
    short* wb = (short*)d_ws;
    dp_dequant_w<<<dim3(K_DIM / 8 / 256, N_DIM), dim3(256), 0, stream>>>(wq, wsc, wb);
    dp_gemm<0><<<dim3(2048), dim3(256), 0, stream>>>(qx, wq, wsc, wb, qxscale,
                                                     residual, bias, out);
  } else {
    dp_gemm<1><<<dim3(2048), dim3(256), 0, stream>>>(qx, wq, wsc, nullptr, qxscale,
                                                     residual, bias, out);
  }
}